// Round 11
// baseline (246.552 us; speedup 1.0000x reference)
//
#include <hip/hip_runtime.h>

#define N_NODES 150000
#define N_EDGES 2400000
#define F_IN    22
#define HID     32
#define N_CLS   6
#define BN_EPS  1e-5f

#define BSHIFT  8
#define BMASK   255
#define NB      ((N_NODES + BMASK) >> BSHIFT)       // 586 buckets of 256 nodes
#define NBLK_BIN 256                                // one bin block per CU
#define CHUNK   ((N_EDGES + NBLK_BIN - 1) / NBLK_BIN)   // 9375 edges per block
#define CHUNK_H 8192
#define NBLK_H  ((N_EDGES + CHUNK_H - 1) / CHUNK_H) // 293 hist blocks
#define EMB_TILE 512
#define NBLK_EMB ((N_NODES + EMB_TILE - 1) / EMB_TILE)  // 293 embed blocks
#define NREP    8                                   // stats replicas

// bf16 round-to-nearest-even, packed storage helpers
__device__ __forceinline__ unsigned bf16rne(float f) {
    unsigned u = __float_as_uint(f);
    return (u + 0x7FFFu + ((u >> 16) & 1u)) >> 16;
}
__device__ __forceinline__ float bflo(unsigned p) { return __uint_as_float(p << 16); }
__device__ __forceinline__ float bfhi(unsigned p) { return __uint_as_float(p & 0xFFFF0000u); }

// ---------------------------------------------------------------------------
// K0: bucket histogram of dst (runs alone, first)
// ---------------------------------------------------------------------------
__global__ void hist_kernel(const int* __restrict__ dst,
                            int* __restrict__ bcnt) {
    __shared__ int hloc[NB];
    for (int t = threadIdx.x; t < NB; t += 256) hloc[t] = 0;
    __syncthreads();
    int base = blockIdx.x * CHUNK_H;
    int end = base + CHUNK_H; if (end > N_EDGES) end = N_EDGES;
    for (int i = base + threadIdx.x; i < end; i += 256)
        atomicAdd(&hloc[dst[i] >> BSHIFT], 1);
    __syncthreads();
    for (int t = threadIdx.x; t < NB; t += 256)
        if (hloc[t]) atomicAdd(&bcnt[t], hloc[t]);
}

// ---------------------------------------------------------------------------
// K1: single-block exclusive scan of NB bucket counts -> boff, bcur;
//     also zeros the stats replicas (absorbs a memset dispatch)
// ---------------------------------------------------------------------------
__global__ void bucket_scan_kernel(const int* __restrict__ bcnt,
                                   int* __restrict__ boff,
                                   int* __restrict__ bcur,
                                   float* __restrict__ stats) {
    int t = threadIdx.x;
    if (t < 64 * NREP) stats[t] = 0.0f;
    __shared__ int s[1024];
    int v0 = (t < NB) ? bcnt[t] : 0;
    s[t] = v0;
    __syncthreads();
#pragma unroll
    for (int o = 1; o < 1024; o <<= 1) {
        int v = (t >= o) ? s[t - o] : 0;
        __syncthreads();
        s[t] += v;                 // inclusive
        __syncthreads();
    }
    if (t < NB) {
        int e = s[t] - v0;         // exclusive
        boff[t] = e;
        bcur[t] = e;
    }
    if (t == NB - 1) boff[NB] = s[t];   // == N_EDGES
}

// ---------------------------------------------------------------------------
// K2 (fused, 512 threads): blocks [0,NBLK_BIN) -> binned append of edges;
//     blocks [NBLK_BIN, NBLK_BIN+NBLK_EMB) -> embed tile of 512 nodes:
//     h = relu(x@W_emb+b_emb)@W_gcn stored as packed bf16 via LDS staging.
//     Shared LDS buffer aliased per role (union) to keep footprint = max.
// ---------------------------------------------------------------------------
__global__ void bin_embed_kernel(const int* __restrict__ src,
                                 const int* __restrict__ dst,
                                 int* __restrict__ bcur,
                                 unsigned int* __restrict__ binned,
                                 const float* __restrict__ x,
                                 const float* __restrict__ W_emb,
                                 const float* __restrict__ b_emb,
                                 const float* __restrict__ W_gcn,
                                 unsigned* __restrict__ hb) {
    __shared__ char smem[44672];
    if (blockIdx.x < NBLK_BIN) {
        int* hloc = (int*)smem;            // NB
        int* base = hloc + NB;             // NB
        int* lcur = base + NB;             // NB
        for (int t = threadIdx.x; t < NB; t += 512) hloc[t] = 0;
        __syncthreads();

        int cbase = blockIdx.x * CHUNK;
        int cend = cbase + CHUNK; if (cend > N_EDGES) cend = N_EDGES;
        for (int i = cbase + threadIdx.x; i < cend; i += 512)
            atomicAdd(&hloc[dst[i] >> BSHIFT], 1);
        __syncthreads();
        for (int t = threadIdx.x; t < NB; t += 512) {
            int c = hloc[t];
            base[t] = c ? atomicAdd(&bcur[t], c) : 0;
            lcur[t] = 0;
        }
        __syncthreads();
        for (int i = cbase + threadIdx.x; i < cend; i += 512) {
            int d = dst[i];
            int b = d >> BSHIFT;
            int r = atomicAdd(&lcur[b], 1);
            binned[base[b] + r] = ((unsigned)(d & BMASK) << 24) | (unsigned)src[i];
        }
    } else {
        float* sWe = (float*)smem;              // 704
        float* sbe = sWe + F_IN * HID;          // 32
        float* sWg = sbe + HID;                 // 1024
        unsigned* sp = (unsigned*)(sWg + HID * HID);  // 512*17 = 34816 B
        for (int t = threadIdx.x; t < F_IN * HID; t += 512) sWe[t] = W_emb[t];
        if (threadIdx.x < HID) sbe[threadIdx.x] = b_emb[threadIdx.x];
        for (int t = threadIdx.x; t < HID * HID; t += 512) sWg[t] = W_gcn[t];
        __syncthreads();

        int eb = blockIdx.x - NBLK_BIN;
        int nbase = eb * EMB_TILE;
        int nvalid = N_NODES - nbase; if (nvalid > EMB_TILE) nvalid = EMB_TILE;
        bool act = (int)threadIdx.x < nvalid;

        if (act) {
            int i = nbase + threadIdx.x;
            float xi[F_IN];
#pragma unroll
            for (int f = 0; f < F_IN; ++f) xi[f] = x[(size_t)i * F_IN + f];

            float h1[HID];
#pragma unroll
            for (int j = 0; j < HID; ++j) {
                float acc = sbe[j];
#pragma unroll
                for (int f = 0; f < F_IN; ++f) acc = fmaf(xi[f], sWe[f * HID + j], acc);
                h1[j] = fmaxf(acc, 0.0f);
            }
#pragma unroll
            for (int jj = 0; jj < HID / 2; ++jj) {
                float a0 = 0.0f, a1 = 0.0f;
#pragma unroll
                for (int f = 0; f < HID; ++f) {
                    a0 = fmaf(h1[f], sWg[f * HID + 2 * jj], a0);
                    a1 = fmaf(h1[f], sWg[f * HID + 2 * jj + 1], a1);
                }
                sp[threadIdx.x * 17 + jj] = bf16rne(a0) | (bf16rne(a1) << 16);
            }
        }
        __syncthreads();

        // cooperative coalesced write of the tile's contiguous 32 KB region
        int total = nvalid * 16;
        size_t gbase = (size_t)nbase * 16;
        for (int L = threadIdx.x; L < total; L += 512)
            hb[gbase + L] = sp[(L >> 4) * 17 + (L & 15)];
    }
}

// ---------------------------------------------------------------------------
// K3: per-bucket local counting sort -> fully dst-sorted sorted_src + off[],
//     plus dis = rsqrt(1+deg).  Writes stay in this bucket's 16 KB window.
// ---------------------------------------------------------------------------
__global__ void bucket_csr_kernel(const int* __restrict__ boff,
                                  const unsigned int* __restrict__ binned,
                                  int* __restrict__ sorted_src,
                                  int* __restrict__ off,
                                  float* __restrict__ dis) {
    __shared__ int s_cnt[256];
    __shared__ int s_scan[256];
    __shared__ int s_cur[256];
    int b = blockIdx.x;
    int t = threadIdx.x;
    int s0 = boff[b], s1 = boff[b + 1];
    int nbase = b << BSHIFT;
    int nnode = N_NODES - nbase; if (nnode > 256) nnode = 256;

    s_cnt[t] = 0;
    __syncthreads();
    for (int k = s0 + t; k < s1; k += 256)
        atomicAdd(&s_cnt[binned[k] >> 24], 1);
    __syncthreads();

    int v = s_cnt[t];
    s_scan[t] = v;
    __syncthreads();
#pragma unroll
    for (int o = 1; o < 256; o <<= 1) {
        int u = (t >= o) ? s_scan[t - o] : 0;
        __syncthreads();
        s_scan[t] += u;            // inclusive
        __syncthreads();
    }
    int excl = s_scan[t] - v;
    s_cur[t] = excl;
    if (t < nnode) {
        off[nbase + t] = s0 + excl;
        dis[nbase + t] = rsqrtf(1.0f + (float)v);
    }
    if (b == NB - 1 && t == 0) off[N_NODES] = N_EDGES;
    __syncthreads();

    // scatter to node-sorted order (writes stay inside [s0,s1) = 16 KB window)
    for (int k = s0 + t; k < s1; k += 256) {
        unsigned p = binned[k];
        int n = (int)(p >> 24);
        int r = atomicAdd(&s_cur[n], 1);
        sorted_src[s0 + r] = (int)(p & 0xFFFFFFu);
    }
}

// ---------------------------------------------------------------------------
// K4: per-node aggregation + fused BN-stats.  8 threads/node (4 features
//     each), bf16 gather rows (64 B/edge), 8-wide ILP.
//     agg[n] = (h[n]*dis[n] + sum_{in(n)} h[s]*dis[s]) * dis[n]
// ---------------------------------------------------------------------------
__global__ void aggregate_kernel(const int* __restrict__ off,
                                 const int* __restrict__ sorted_src,
                                 const unsigned* __restrict__ hb,
                                 const float* __restrict__ dis,
                                 float* __restrict__ agg,
                                 float* __restrict__ stats) {
    int t = blockIdx.x * blockDim.x + threadIdx.x;
    int node = t >> 3;
    int c = t & 7;
    bool active = node < N_NODES;

    float4 ps = {0.f, 0.f, 0.f, 0.f};
    float4 pq = {0.f, 0.f, 0.f, 0.f};

    if (active) {
        const uint2* hrow = reinterpret_cast<const uint2*>(hb);
        float dn = dis[node];
        uint2 hp = hrow[(size_t)node * 8 + c];
        float4 a0, a1, a2, a3;
        a0.x = bflo(hp.x) * dn; a0.y = bfhi(hp.x) * dn;
        a0.z = bflo(hp.y) * dn; a0.w = bfhi(hp.y) * dn;
        a1 = a2 = a3 = make_float4(0.f, 0.f, 0.f, 0.f);

        int b = off[node], e = off[node + 1];
        int k = b;
        for (; k + 8 <= e; k += 8) {
            int s0 = sorted_src[k],     s1 = sorted_src[k + 1];
            int s2 = sorted_src[k + 2], s3 = sorted_src[k + 3];
            int s4 = sorted_src[k + 4], s5 = sorted_src[k + 5];
            int s6 = sorted_src[k + 6], s7 = sorted_src[k + 7];
            float d0 = dis[s0], d1 = dis[s1], d2 = dis[s2], d3 = dis[s3];
            float d4 = dis[s4], d5 = dis[s5], d6 = dis[s6], d7 = dis[s7];
            uint2 v0 = hrow[(size_t)s0 * 8 + c];
            uint2 v1 = hrow[(size_t)s1 * 8 + c];
            uint2 v2 = hrow[(size_t)s2 * 8 + c];
            uint2 v3 = hrow[(size_t)s3 * 8 + c];
            uint2 v4 = hrow[(size_t)s4 * 8 + c];
            uint2 v5 = hrow[(size_t)s5 * 8 + c];
            uint2 v6 = hrow[(size_t)s6 * 8 + c];
            uint2 v7 = hrow[(size_t)s7 * 8 + c];
            a0.x = fmaf(bflo(v0.x), d0, a0.x); a0.y = fmaf(bfhi(v0.x), d0, a0.y);
            a0.z = fmaf(bflo(v0.y), d0, a0.z); a0.w = fmaf(bfhi(v0.y), d0, a0.w);
            a1.x = fmaf(bflo(v1.x), d1, a1.x); a1.y = fmaf(bfhi(v1.x), d1, a1.y);
            a1.z = fmaf(bflo(v1.y), d1, a1.z); a1.w = fmaf(bfhi(v1.y), d1, a1.w);
            a2.x = fmaf(bflo(v2.x), d2, a2.x); a2.y = fmaf(bfhi(v2.x), d2, a2.y);
            a2.z = fmaf(bflo(v2.y), d2, a2.z); a2.w = fmaf(bfhi(v2.y), d2, a2.w);
            a3.x = fmaf(bflo(v3.x), d3, a3.x); a3.y = fmaf(bfhi(v3.x), d3, a3.y);
            a3.z = fmaf(bflo(v3.y), d3, a3.z); a3.w = fmaf(bfhi(v3.y), d3, a3.w);
            a0.x = fmaf(bflo(v4.x), d4, a0.x); a0.y = fmaf(bfhi(v4.x), d4, a0.y);
            a0.z = fmaf(bflo(v4.y), d4, a0.z); a0.w = fmaf(bfhi(v4.y), d4, a0.w);
            a1.x = fmaf(bflo(v5.x), d5, a1.x); a1.y = fmaf(bfhi(v5.x), d5, a1.y);
            a1.z = fmaf(bflo(v5.y), d5, a1.z); a1.w = fmaf(bfhi(v5.y), d5, a1.w);
            a2.x = fmaf(bflo(v6.x), d6, a2.x); a2.y = fmaf(bfhi(v6.x), d6, a2.y);
            a2.z = fmaf(bflo(v6.y), d6, a2.z); a2.w = fmaf(bfhi(v6.y), d6, a2.w);
            a3.x = fmaf(bflo(v7.x), d7, a3.x); a3.y = fmaf(bfhi(v7.x), d7, a3.y);
            a3.z = fmaf(bflo(v7.y), d7, a3.z); a3.w = fmaf(bfhi(v7.y), d7, a3.w);
        }
        for (; k < e; ++k) {
            int s = sorted_src[k];
            float d = dis[s];
            uint2 v = hrow[(size_t)s * 8 + c];
            a0.x = fmaf(bflo(v.x), d, a0.x); a0.y = fmaf(bfhi(v.x), d, a0.y);
            a0.z = fmaf(bflo(v.y), d, a0.z); a0.w = fmaf(bfhi(v.y), d, a0.w);
        }
        float4 o;
        o.x = (a0.x + a1.x + a2.x + a3.x) * dn;
        o.y = (a0.y + a1.y + a2.y + a3.y) * dn;
        o.z = (a0.z + a1.z + a2.z + a3.z) * dn;
        o.w = (a0.w + a1.w + a2.w + a3.w) * dn;
        reinterpret_cast<float4*>(agg)[(size_t)node * 8 + c] = o;
        ps = o;
        pq.x = o.x * o.x; pq.y = o.y * o.y; pq.z = o.z * o.z; pq.w = o.w * o.w;
    }

    // block-level stats reduce (all 256 threads reach barriers)
    __shared__ float S[256 * 4];
    __shared__ float Q[256 * 4];
    S[threadIdx.x * 4 + 0] = ps.x; S[threadIdx.x * 4 + 1] = ps.y;
    S[threadIdx.x * 4 + 2] = ps.z; S[threadIdx.x * 4 + 3] = ps.w;
    Q[threadIdx.x * 4 + 0] = pq.x; Q[threadIdx.x * 4 + 1] = pq.y;
    Q[threadIdx.x * 4 + 2] = pq.z; Q[threadIdx.x * 4 + 3] = pq.w;
    __syncthreads();
    if (threadIdx.x < 32) {
        int cc = threadIdx.x >> 2, j = threadIdx.x & 3;   // feature f = 4*cc+j
        float s = 0.0f, q = 0.0f;
#pragma unroll
        for (int w = 0; w < 32; ++w) {                    // threads with tid&7==cc
            int tid = (w << 3) | cc;
            s += S[tid * 4 + j];
            q += Q[tid * 4 + j];
        }
        float* rep = stats + 64 * (blockIdx.x & (NREP - 1));
        atomicAdd(&rep[threadIdx.x], s);
        atomicAdd(&rep[32 + threadIdx.x], q);
    }
}

// ---------------------------------------------------------------------------
// K5: out = relu(agg*A + B) @ W_cls + b_cls   (BN fold from NREP stat replicas)
// ---------------------------------------------------------------------------
__global__ void cls_kernel(const float* __restrict__ agg,
                           const float* __restrict__ stats,
                           const float* __restrict__ gamma,
                           const float* __restrict__ beta,
                           const float* __restrict__ W_cls,
                           const float* __restrict__ b_cls,
                           float* __restrict__ out) {
    __shared__ float sA[HID];
    __shared__ float sB[HID];
    __shared__ float sW[HID * N_CLS];
    __shared__ float sb[N_CLS];
    if (threadIdx.x < HID) {
        float sum = 0.0f, sq = 0.0f;
#pragma unroll
        for (int r = 0; r < NREP; ++r) {
            sum += stats[r * 64 + threadIdx.x];
            sq  += stats[r * 64 + 32 + threadIdx.x];
        }
        const float invN = 1.0f / (float)N_NODES;
        float mean = sum * invN;
        float var = sq * invN - mean * mean;
        float inv = rsqrtf(var + BN_EPS);
        float A = gamma[threadIdx.x] * inv;
        sA[threadIdx.x] = A;
        sB[threadIdx.x] = beta[threadIdx.x] - mean * A;
    }
    for (int t = threadIdx.x; t < HID * N_CLS; t += blockDim.x) sW[t] = W_cls[t];
    if (threadIdx.x < N_CLS) sb[threadIdx.x] = b_cls[threadIdx.x];
    __syncthreads();

    int i = blockIdx.x * blockDim.x + threadIdx.x;
    if (i >= N_NODES) return;

    float acc[N_CLS];
#pragma unroll
    for (int c = 0; c < N_CLS; ++c) acc[c] = sb[c];
#pragma unroll
    for (int f = 0; f < HID; ++f) {
        float t = fmaxf(fmaf(agg[(size_t)i * HID + f], sA[f], sB[f]), 0.0f);
#pragma unroll
        for (int c = 0; c < N_CLS; ++c) acc[c] = fmaf(t, sW[f * N_CLS + c], acc[c]);
    }
#pragma unroll
    for (int c = 0; c < N_CLS; ++c) out[(size_t)i * N_CLS + c] = acc[c];
}

// ---------------------------------------------------------------------------
extern "C" void kernel_launch(void* const* d_in, const int* in_sizes, int n_in,
                              void* d_out, int out_size, void* d_ws, size_t ws_size,
                              hipStream_t stream) {
    const float* x     = (const float*)d_in[0];
    const int*   edge  = (const int*)d_in[1];   // [2, E] int32
    const float* W_emb = (const float*)d_in[2];
    const float* b_emb = (const float*)d_in[3];
    const float* W_gcn = (const float*)d_in[4];
    // d_in[5] = b_gcn: per-feature constant, cancels exactly in BatchNorm -> skip
    const float* gamma = (const float*)d_in[6];
    const float* beta  = (const float*)d_in[7];
    const float* W_cls = (const float*)d_in[8];
    const float* b_cls = (const float*)d_in[9];
    float* out = (float*)d_out;

    // workspace layout (~49 MB)
    unsigned*     hb         = (unsigned*)d_ws;                 // N*HID/2 uints (bf16 x2)
    float*        agg        = (float*)(hb + (size_t)N_NODES * HID / 2);  // N*HID
    float*        dis        = agg + (size_t)N_NODES * HID;     // N
    int*          off        = (int*)(dis + N_NODES);           // N+1
    int*          bcnt       = off + N_NODES + 1;               // NB
    int*          boff       = bcnt + NB;                       // NB+1
    int*          bcur       = boff + NB + 1;                   // NB
    unsigned int* binned     = (unsigned int*)(bcur + NB);      // E
    int*          sorted_src = (int*)(binned + N_EDGES);        // E
    float*        stats      = (float*)(sorted_src + N_EDGES);  // 64*NREP

    hipMemsetAsync(bcnt, 0, NB * sizeof(int), stream);

    const int* src = edge;
    const int* dst = edge + N_EDGES;

    hist_kernel<<<NBLK_H, 256, 0, stream>>>(dst, bcnt);
    bucket_scan_kernel<<<1, 1024, 0, stream>>>(bcnt, boff, bcur, stats);
    bin_embed_kernel<<<NBLK_BIN + NBLK_EMB, 512, 0, stream>>>(src, dst, bcur, binned,
                                                              x, W_emb, b_emb, W_gcn, hb);
    bucket_csr_kernel<<<NB, 256, 0, stream>>>(boff, binned, sorted_src, off, dis);
    aggregate_kernel<<<(N_NODES * 8 + 255) / 256, 256, 0, stream>>>(off, sorted_src,
                                                                    hb, dis, agg, stats);
    cls_kernel<<<(N_NODES + 255) / 256, 256, 0, stream>>>(agg, stats, gamma, beta,
                                                          W_cls, b_cls, out);
}

// Round 12
// 154.029 us; speedup vs baseline: 1.6007x; 1.6007x over previous
//
#include <hip/hip_runtime.h>

#define N_NODES 150000
#define N_EDGES 2400000
#define F_IN    22
#define HID     32
#define N_CLS   6
#define BN_EPS  1e-5f

#define BSHIFT  8
#define BMASK   255
#define NB      ((N_NODES + BMASK) >> BSHIFT)       // 586 buckets of 256 nodes
#define NBLK_BIN 256                                // one bin block per CU
#define CHUNK   ((N_EDGES + NBLK_BIN - 1) / NBLK_BIN)   // 9375 edges per block
#define CHUNK_H 8192
#define NBLK_H  ((N_EDGES + CHUNK_H - 1) / CHUNK_H) // 293 hist blocks
#define EMB_NPB 64                                  // nodes per embed block
#define NBLK_EMB ((N_NODES + EMB_NPB - 1) / EMB_NPB)    // 2344 embed blocks
#define NREP    8                                   // stats replicas

// bf16 round-to-nearest-even, packed storage helpers
__device__ __forceinline__ unsigned bf16rne(float f) {
    unsigned u = __float_as_uint(f);
    return (u + 0x7FFFu + ((u >> 16) & 1u)) >> 16;
}
__device__ __forceinline__ float bflo(unsigned p) { return __uint_as_float(p << 16); }
__device__ __forceinline__ float bfhi(unsigned p) { return __uint_as_float(p & 0xFFFF0000u); }

// ---------------------------------------------------------------------------
// K0 (fused): blocks [0,NBLK_EMB): embed 64 nodes with 4 threads/node —
//   thread (n=t>>2, q=t&3) computes h1[8] slice then output[8] slice via LDS.
//   Short phases + 2344 blocks -> latency hidden by occupancy, not per-thread.
//   blocks [NBLK_EMB, +NBLK_H): bucket histogram of dst (proven benign fusion).
// ---------------------------------------------------------------------------
__global__ void embed_hist_kernel(const float* __restrict__ x,
                                  const float* __restrict__ W_emb,
                                  const float* __restrict__ b_emb,
                                  const float* __restrict__ W_gcn,
                                  unsigned* __restrict__ hb,
                                  const int* __restrict__ dst,
                                  int* __restrict__ bcnt) {
    if (blockIdx.x < NBLK_EMB) {
        __shared__ float sWe[F_IN * HID];        // 2816 B
        __shared__ float sbe[HID];
        __shared__ float sWg[HID * HID];         // 4096 B
        __shared__ float sx[EMB_NPB * 23];       // 5888 B (pad 23, gcd(23,32)=1)
        __shared__ float sh1[EMB_NPB * 33];      // 8448 B (pad 33)
        __shared__ unsigned sp[EMB_NPB * 17];    // 4352 B (pad 17)
        for (int t = threadIdx.x; t < F_IN * HID; t += 256) sWe[t] = W_emb[t];
        if (threadIdx.x < HID) sbe[threadIdx.x] = b_emb[threadIdx.x];
        for (int t = threadIdx.x; t < HID * HID; t += 256) sWg[t] = W_gcn[t];

        int nbase = blockIdx.x * EMB_NPB;
        int nvalid = N_NODES - nbase; if (nvalid > EMB_NPB) nvalid = EMB_NPB;

        // coalesced stage of this block's x rows
        {
            const float* xg = x + (size_t)nbase * F_IN;
            int totalx = nvalid * F_IN;
            for (int L = threadIdx.x; L < totalx; L += 256)
                sx[(L / F_IN) * 23 + (L % F_IN)] = xg[L];
        }
        __syncthreads();

        int n = threadIdx.x >> 2;       // node within block
        int q = threadIdx.x & 3;        // 8-feature slice
        bool act = n < nvalid;

        if (act) {                      // phase 2: h1 slice (22x8 FMA)
#pragma unroll
            for (int j = 0; j < 8; ++j) {
                float acc = sbe[q * 8 + j];
#pragma unroll
                for (int f = 0; f < F_IN; ++f)
                    acc = fmaf(sx[n * 23 + f], sWe[f * HID + q * 8 + j], acc);
                sh1[n * 33 + q * 8 + j] = fmaxf(acc, 0.0f);
            }
        }
        __syncthreads();

        if (act) {                      // phase 3: output slice (32x8 FMA)
            float o[8];
#pragma unroll
            for (int j = 0; j < 8; ++j) o[j] = 0.0f;
#pragma unroll
            for (int f = 0; f < HID; ++f) {
                float hv = sh1[n * 33 + f];
#pragma unroll
                for (int j = 0; j < 8; ++j)
                    o[j] = fmaf(hv, sWg[f * HID + q * 8 + j], o[j]);
            }
#pragma unroll
            for (int jj = 0; jj < 4; ++jj)
                sp[n * 17 + q * 4 + jj] = bf16rne(o[2 * jj]) | (bf16rne(o[2 * jj + 1]) << 16);
        }
        __syncthreads();

        // cooperative coalesced write of the block's contiguous 4 KB region
        int total = nvalid * 16;
        size_t gbase = (size_t)nbase * 16;
        for (int L = threadIdx.x; L < total; L += 256)
            hb[gbase + L] = sp[(L >> 4) * 17 + (L & 15)];
    } else {
        __shared__ int hloc[NB];
        for (int t = threadIdx.x; t < NB; t += 256) hloc[t] = 0;
        __syncthreads();
        int base = (blockIdx.x - NBLK_EMB) * CHUNK_H;
        int end = base + CHUNK_H; if (end > N_EDGES) end = N_EDGES;
        for (int i = base + threadIdx.x; i < end; i += 256)
            atomicAdd(&hloc[dst[i] >> BSHIFT], 1);
        __syncthreads();
        for (int t = threadIdx.x; t < NB; t += 256)
            if (hloc[t]) atomicAdd(&bcnt[t], hloc[t]);
    }
}

// ---------------------------------------------------------------------------
// K1: single-block exclusive scan of NB (=586) bucket counts -> boff, bcur;
//     also zeros the stats replicas (absorbs a memset dispatch)
// ---------------------------------------------------------------------------
__global__ void bucket_scan_kernel(const int* __restrict__ bcnt,
                                   int* __restrict__ boff,
                                   int* __restrict__ bcur,
                                   float* __restrict__ stats) {
    int t = threadIdx.x;
    if (t < 64 * NREP) stats[t] = 0.0f;
    __shared__ int s[1024];
    int v0 = (t < NB) ? bcnt[t] : 0;
    s[t] = v0;
    __syncthreads();
#pragma unroll
    for (int o = 1; o < 1024; o <<= 1) {
        int v = (t >= o) ? s[t - o] : 0;
        __syncthreads();
        s[t] += v;                 // inclusive
        __syncthreads();
    }
    if (t < NB) {
        int e = s[t] - v0;         // exclusive
        boff[t] = e;
        bcur[t] = e;
    }
    if (t == NB - 1) boff[NB] = s[t];   // == N_EDGES
}

// ---------------------------------------------------------------------------
// K2: binned append, 256 blocks, 512 threads — runs ALONE (write-combining
//     needs the L2 to itself; round-11 fusion with embed thrashed it).
//     packed = (dst & 255) << 24 | src   (src < 2^24)
// ---------------------------------------------------------------------------
__global__ void bin_edges_kernel(const int* __restrict__ src,
                                 const int* __restrict__ dst,
                                 int* __restrict__ bcur,
                                 unsigned int* __restrict__ binned) {
    __shared__ int hloc[NB];
    __shared__ int base[NB];
    __shared__ int lcur[NB];
    for (int t = threadIdx.x; t < NB; t += 512) hloc[t] = 0;
    __syncthreads();

    int cbase = blockIdx.x * CHUNK;
    int cend = cbase + CHUNK; if (cend > N_EDGES) cend = N_EDGES;
    for (int i = cbase + threadIdx.x; i < cend; i += 512)
        atomicAdd(&hloc[dst[i] >> BSHIFT], 1);
    __syncthreads();
    for (int t = threadIdx.x; t < NB; t += 512) {
        int c = hloc[t];
        base[t] = c ? atomicAdd(&bcur[t], c) : 0;
        lcur[t] = 0;
    }
    __syncthreads();
    for (int i = cbase + threadIdx.x; i < cend; i += 512) {
        int d = dst[i];
        int b = d >> BSHIFT;
        int r = atomicAdd(&lcur[b], 1);
        binned[base[b] + r] = ((unsigned)(d & BMASK) << 24) | (unsigned)src[i];
    }
}

// ---------------------------------------------------------------------------
// K3: per-bucket local counting sort -> fully dst-sorted sorted_src + off[],
//     plus dis = rsqrt(1+deg).  Writes stay in this bucket's 16 KB window.
// ---------------------------------------------------------------------------
__global__ void bucket_csr_kernel(const int* __restrict__ boff,
                                  const unsigned int* __restrict__ binned,
                                  int* __restrict__ sorted_src,
                                  int* __restrict__ off,
                                  float* __restrict__ dis) {
    __shared__ int s_cnt[256];
    __shared__ int s_scan[256];
    __shared__ int s_cur[256];
    int b = blockIdx.x;
    int t = threadIdx.x;
    int s0 = boff[b], s1 = boff[b + 1];
    int nbase = b << BSHIFT;
    int nnode = N_NODES - nbase; if (nnode > 256) nnode = 256;

    s_cnt[t] = 0;
    __syncthreads();
    for (int k = s0 + t; k < s1; k += 256)
        atomicAdd(&s_cnt[binned[k] >> 24], 1);
    __syncthreads();

    int v = s_cnt[t];
    s_scan[t] = v;
    __syncthreads();
#pragma unroll
    for (int o = 1; o < 256; o <<= 1) {
        int u = (t >= o) ? s_scan[t - o] : 0;
        __syncthreads();
        s_scan[t] += u;            // inclusive
        __syncthreads();
    }
    int excl = s_scan[t] - v;
    s_cur[t] = excl;
    if (t < nnode) {
        off[nbase + t] = s0 + excl;
        dis[nbase + t] = rsqrtf(1.0f + (float)v);
    }
    if (b == NB - 1 && t == 0) off[N_NODES] = N_EDGES;
    __syncthreads();

    // scatter to node-sorted order (writes stay inside [s0,s1) = 16 KB window)
    for (int k = s0 + t; k < s1; k += 256) {
        unsigned p = binned[k];
        int n = (int)(p >> 24);
        int r = atomicAdd(&s_cur[n], 1);
        sorted_src[s0 + r] = (int)(p & 0xFFFFFFu);
    }
}

// ---------------------------------------------------------------------------
// K4: per-node aggregation + fused BN-stats.  8 threads/node (4 features
//     each), bf16 gather rows (64 B/edge), 8-wide ILP.
//     agg[n] = (h[n]*dis[n] + sum_{in(n)} h[s]*dis[s]) * dis[n]
// ---------------------------------------------------------------------------
__global__ void aggregate_kernel(const int* __restrict__ off,
                                 const int* __restrict__ sorted_src,
                                 const unsigned* __restrict__ hb,
                                 const float* __restrict__ dis,
                                 float* __restrict__ agg,
                                 float* __restrict__ stats) {
    int t = blockIdx.x * blockDim.x + threadIdx.x;
    int node = t >> 3;
    int c = t & 7;
    bool active = node < N_NODES;

    float4 ps = {0.f, 0.f, 0.f, 0.f};
    float4 pq = {0.f, 0.f, 0.f, 0.f};

    if (active) {
        const uint2* hrow = reinterpret_cast<const uint2*>(hb);
        float dn = dis[node];
        uint2 hp = hrow[(size_t)node * 8 + c];
        float4 a0, a1, a2, a3;
        a0.x = bflo(hp.x) * dn; a0.y = bfhi(hp.x) * dn;
        a0.z = bflo(hp.y) * dn; a0.w = bfhi(hp.y) * dn;
        a1 = a2 = a3 = make_float4(0.f, 0.f, 0.f, 0.f);

        int b = off[node], e = off[node + 1];
        int k = b;
        for (; k + 8 <= e; k += 8) {
            int s0 = sorted_src[k],     s1 = sorted_src[k + 1];
            int s2 = sorted_src[k + 2], s3 = sorted_src[k + 3];
            int s4 = sorted_src[k + 4], s5 = sorted_src[k + 5];
            int s6 = sorted_src[k + 6], s7 = sorted_src[k + 7];
            float d0 = dis[s0], d1 = dis[s1], d2 = dis[s2], d3 = dis[s3];
            float d4 = dis[s4], d5 = dis[s5], d6 = dis[s6], d7 = dis[s7];
            uint2 v0 = hrow[(size_t)s0 * 8 + c];
            uint2 v1 = hrow[(size_t)s1 * 8 + c];
            uint2 v2 = hrow[(size_t)s2 * 8 + c];
            uint2 v3 = hrow[(size_t)s3 * 8 + c];
            uint2 v4 = hrow[(size_t)s4 * 8 + c];
            uint2 v5 = hrow[(size_t)s5 * 8 + c];
            uint2 v6 = hrow[(size_t)s6 * 8 + c];
            uint2 v7 = hrow[(size_t)s7 * 8 + c];
            a0.x = fmaf(bflo(v0.x), d0, a0.x); a0.y = fmaf(bfhi(v0.x), d0, a0.y);
            a0.z = fmaf(bflo(v0.y), d0, a0.z); a0.w = fmaf(bfhi(v0.y), d0, a0.w);
            a1.x = fmaf(bflo(v1.x), d1, a1.x); a1.y = fmaf(bfhi(v1.x), d1, a1.y);
            a1.z = fmaf(bflo(v1.y), d1, a1.z); a1.w = fmaf(bfhi(v1.y), d1, a1.w);
            a2.x = fmaf(bflo(v2.x), d2, a2.x); a2.y = fmaf(bfhi(v2.x), d2, a2.y);
            a2.z = fmaf(bflo(v2.y), d2, a2.z); a2.w = fmaf(bfhi(v2.y), d2, a2.w);
            a3.x = fmaf(bflo(v3.x), d3, a3.x); a3.y = fmaf(bfhi(v3.x), d3, a3.y);
            a3.z = fmaf(bflo(v3.y), d3, a3.z); a3.w = fmaf(bfhi(v3.y), d3, a3.w);
            a0.x = fmaf(bflo(v4.x), d4, a0.x); a0.y = fmaf(bfhi(v4.x), d4, a0.y);
            a0.z = fmaf(bflo(v4.y), d4, a0.z); a0.w = fmaf(bfhi(v4.y), d4, a0.w);
            a1.x = fmaf(bflo(v5.x), d5, a1.x); a1.y = fmaf(bfhi(v5.x), d5, a1.y);
            a1.z = fmaf(bflo(v5.y), d5, a1.z); a1.w = fmaf(bfhi(v5.y), d5, a1.w);
            a2.x = fmaf(bflo(v6.x), d6, a2.x); a2.y = fmaf(bfhi(v6.x), d6, a2.y);
            a2.z = fmaf(bflo(v6.y), d6, a2.z); a2.w = fmaf(bfhi(v6.y), d6, a2.w);
            a3.x = fmaf(bflo(v7.x), d7, a3.x); a3.y = fmaf(bfhi(v7.x), d7, a3.y);
            a3.z = fmaf(bflo(v7.y), d7, a3.z); a3.w = fmaf(bfhi(v7.y), d7, a3.w);
        }
        for (; k < e; ++k) {
            int s = sorted_src[k];
            float d = dis[s];
            uint2 v = hrow[(size_t)s * 8 + c];
            a0.x = fmaf(bflo(v.x), d, a0.x); a0.y = fmaf(bfhi(v.x), d, a0.y);
            a0.z = fmaf(bflo(v.y), d, a0.z); a0.w = fmaf(bfhi(v.y), d, a0.w);
        }
        float4 o;
        o.x = (a0.x + a1.x + a2.x + a3.x) * dn;
        o.y = (a0.y + a1.y + a2.y + a3.y) * dn;
        o.z = (a0.z + a1.z + a2.z + a3.z) * dn;
        o.w = (a0.w + a1.w + a2.w + a3.w) * dn;
        reinterpret_cast<float4*>(agg)[(size_t)node * 8 + c] = o;
        ps = o;
        pq.x = o.x * o.x; pq.y = o.y * o.y; pq.z = o.z * o.z; pq.w = o.w * o.w;
    }

    // block-level stats reduce (all 256 threads reach barriers)
    __shared__ float S[256 * 4];
    __shared__ float Q[256 * 4];
    S[threadIdx.x * 4 + 0] = ps.x; S[threadIdx.x * 4 + 1] = ps.y;
    S[threadIdx.x * 4 + 2] = ps.z; S[threadIdx.x * 4 + 3] = ps.w;
    Q[threadIdx.x * 4 + 0] = pq.x; Q[threadIdx.x * 4 + 1] = pq.y;
    Q[threadIdx.x * 4 + 2] = pq.z; Q[threadIdx.x * 4 + 3] = pq.w;
    __syncthreads();
    if (threadIdx.x < 32) {
        int cc = threadIdx.x >> 2, j = threadIdx.x & 3;   // feature f = 4*cc+j
        float s = 0.0f, q = 0.0f;
#pragma unroll
        for (int w = 0; w < 32; ++w) {                    // threads with tid&7==cc
            int tid = (w << 3) | cc;
            s += S[tid * 4 + j];
            q += Q[tid * 4 + j];
        }
        float* rep = stats + 64 * (blockIdx.x & (NREP - 1));
        atomicAdd(&rep[threadIdx.x], s);
        atomicAdd(&rep[32 + threadIdx.x], q);
    }
}

// ---------------------------------------------------------------------------
// K5: out = relu(agg*A + B) @ W_cls + b_cls   (BN fold from NREP stat replicas)
// ---------------------------------------------------------------------------
__global__ void cls_kernel(const float* __restrict__ agg,
                           const float* __restrict__ stats,
                           const float* __restrict__ gamma,
                           const float* __restrict__ beta,
                           const float* __restrict__ W_cls,
                           const float* __restrict__ b_cls,
                           float* __restrict__ out) {
    __shared__ float sA[HID];
    __shared__ float sB[HID];
    __shared__ float sW[HID * N_CLS];
    __shared__ float sb[N_CLS];
    if (threadIdx.x < HID) {
        float sum = 0.0f, sq = 0.0f;
#pragma unroll
        for (int r = 0; r < NREP; ++r) {
            sum += stats[r * 64 + threadIdx.x];
            sq  += stats[r * 64 + 32 + threadIdx.x];
        }
        const float invN = 1.0f / (float)N_NODES;
        float mean = sum * invN;
        float var = sq * invN - mean * mean;
        float inv = rsqrtf(var + BN_EPS);
        float A = gamma[threadIdx.x] * inv;
        sA[threadIdx.x] = A;
        sB[threadIdx.x] = beta[threadIdx.x] - mean * A;
    }
    for (int t = threadIdx.x; t < HID * N_CLS; t += blockDim.x) sW[t] = W_cls[t];
    if (threadIdx.x < N_CLS) sb[threadIdx.x] = b_cls[threadIdx.x];
    __syncthreads();

    int i = blockIdx.x * blockDim.x + threadIdx.x;
    if (i >= N_NODES) return;

    float acc[N_CLS];
#pragma unroll
    for (int c = 0; c < N_CLS; ++c) acc[c] = sb[c];
#pragma unroll
    for (int f = 0; f < HID; ++f) {
        float t = fmaxf(fmaf(agg[(size_t)i * HID + f], sA[f], sB[f]), 0.0f);
#pragma unroll
        for (int c = 0; c < N_CLS; ++c) acc[c] = fmaf(t, sW[f * N_CLS + c], acc[c]);
    }
#pragma unroll
    for (int c = 0; c < N_CLS; ++c) out[(size_t)i * N_CLS + c] = acc[c];
}

// ---------------------------------------------------------------------------
extern "C" void kernel_launch(void* const* d_in, const int* in_sizes, int n_in,
                              void* d_out, int out_size, void* d_ws, size_t ws_size,
                              hipStream_t stream) {
    const float* x     = (const float*)d_in[0];
    const int*   edge  = (const int*)d_in[1];   // [2, E] int32
    const float* W_emb = (const float*)d_in[2];
    const float* b_emb = (const float*)d_in[3];
    const float* W_gcn = (const float*)d_in[4];
    // d_in[5] = b_gcn: per-feature constant, cancels exactly in BatchNorm -> skip
    const float* gamma = (const float*)d_in[6];
    const float* beta  = (const float*)d_in[7];
    const float* W_cls = (const float*)d_in[8];
    const float* b_cls = (const float*)d_in[9];
    float* out = (float*)d_out;

    // workspace layout (~49 MB)
    unsigned*     hb         = (unsigned*)d_ws;                 // N*HID/2 uints (bf16 x2)
    float*        agg        = (float*)(hb + (size_t)N_NODES * HID / 2);  // N*HID
    float*        dis        = agg + (size_t)N_NODES * HID;     // N
    int*          off        = (int*)(dis + N_NODES);           // N+1
    int*          bcnt       = off + N_NODES + 1;               // NB
    int*          boff       = bcnt + NB;                       // NB+1
    int*          bcur       = boff + NB + 1;                   // NB
    unsigned int* binned     = (unsigned int*)(bcur + NB);      // E
    int*          sorted_src = (int*)(binned + N_EDGES);        // E
    float*        stats      = (float*)(sorted_src + N_EDGES);  // 64*NREP

    hipMemsetAsync(bcnt, 0, NB * sizeof(int), stream);

    const int* src = edge;
    const int* dst = edge + N_EDGES;

    embed_hist_kernel<<<NBLK_EMB + NBLK_H, 256, 0, stream>>>(x, W_emb, b_emb, W_gcn,
                                                             hb, dst, bcnt);
    bucket_scan_kernel<<<1, 1024, 0, stream>>>(bcnt, boff, bcur, stats);
    bin_edges_kernel<<<NBLK_BIN, 512, 0, stream>>>(src, dst, bcur, binned);
    bucket_csr_kernel<<<NB, 256, 0, stream>>>(boff, binned, sorted_src, off, dis);
    aggregate_kernel<<<(N_NODES * 8 + 255) / 256, 256, 0, stream>>>(off, sorted_src,
                                                                    hb, dis, agg, stats);
    cls_kernel<<<(N_NODES + 255) / 256, 256, 0, stream>>>(agg, stats, gamma, beta,
                                                          W_cls, b_cls, out);
}

// Round 13
// 150.010 us; speedup vs baseline: 1.6436x; 1.0268x over previous
//
#include <hip/hip_runtime.h>

#define N_NODES 150000
#define N_EDGES 2400000
#define F_IN    22
#define HID     32
#define N_CLS   6
#define BN_EPS  1e-5f

#define BSHIFT  8
#define BMASK   255
#define NB      ((N_NODES + BMASK) >> BSHIFT)       // 586 buckets of 256 nodes
#define NBLK_BIN 256                                // one bin block per CU
#define CHUNK   ((N_EDGES + NBLK_BIN - 1) / NBLK_BIN)   // 9375 edges per block
#define CHUNK_H 8192
#define NBLK_H  ((N_EDGES + CHUNK_H - 1) / CHUNK_H) // 293 hist blocks
#define EMB_NPB 64                                  // nodes per embed block
#define NBLK_EMB ((N_NODES + EMB_NPB - 1) / EMB_NPB)    // 2344 embed blocks
#define NREP    8                                   // stats replicas

// bf16 round-to-nearest-even, packed storage helpers
__device__ __forceinline__ unsigned bf16rne(float f) {
    unsigned u = __float_as_uint(f);
    return (u + 0x7FFFu + ((u >> 16) & 1u)) >> 16;
}
__device__ __forceinline__ float bflo(unsigned p) { return __uint_as_float(p << 16); }
__device__ __forceinline__ float bfhi(unsigned p) { return __uint_as_float(p & 0xFFFF0000u); }

// ---------------------------------------------------------------------------
// K0 (fused): blocks [0,NBLK_EMB): embed 64 nodes with 4 threads/node.
//   blocks [NBLK_EMB, +NBLK_H): bucket histogram of dst.
// ---------------------------------------------------------------------------
__global__ void embed_hist_kernel(const float* __restrict__ x,
                                  const float* __restrict__ W_emb,
                                  const float* __restrict__ b_emb,
                                  const float* __restrict__ W_gcn,
                                  unsigned* __restrict__ hb,
                                  const int* __restrict__ dst,
                                  int* __restrict__ bcnt) {
    if (blockIdx.x < NBLK_EMB) {
        __shared__ float sWe[F_IN * HID];
        __shared__ float sbe[HID];
        __shared__ float sWg[HID * HID];
        __shared__ float sx[EMB_NPB * 23];
        __shared__ float sh1[EMB_NPB * 33];
        __shared__ unsigned sp[EMB_NPB * 17];
        for (int t = threadIdx.x; t < F_IN * HID; t += 256) sWe[t] = W_emb[t];
        if (threadIdx.x < HID) sbe[threadIdx.x] = b_emb[threadIdx.x];
        for (int t = threadIdx.x; t < HID * HID; t += 256) sWg[t] = W_gcn[t];

        int nbase = blockIdx.x * EMB_NPB;
        int nvalid = N_NODES - nbase; if (nvalid > EMB_NPB) nvalid = EMB_NPB;

        {
            const float* xg = x + (size_t)nbase * F_IN;
            int totalx = nvalid * F_IN;
            for (int L = threadIdx.x; L < totalx; L += 256)
                sx[(L / F_IN) * 23 + (L % F_IN)] = xg[L];
        }
        __syncthreads();

        int n = threadIdx.x >> 2;
        int q = threadIdx.x & 3;
        bool act = n < nvalid;

        if (act) {
#pragma unroll
            for (int j = 0; j < 8; ++j) {
                float acc = sbe[q * 8 + j];
#pragma unroll
                for (int f = 0; f < F_IN; ++f)
                    acc = fmaf(sx[n * 23 + f], sWe[f * HID + q * 8 + j], acc);
                sh1[n * 33 + q * 8 + j] = fmaxf(acc, 0.0f);
            }
        }
        __syncthreads();

        if (act) {
            float o[8];
#pragma unroll
            for (int j = 0; j < 8; ++j) o[j] = 0.0f;
#pragma unroll
            for (int f = 0; f < HID; ++f) {
                float hv = sh1[n * 33 + f];
#pragma unroll
                for (int j = 0; j < 8; ++j)
                    o[j] = fmaf(hv, sWg[f * HID + q * 8 + j], o[j]);
            }
#pragma unroll
            for (int jj = 0; jj < 4; ++jj)
                sp[n * 17 + q * 4 + jj] = bf16rne(o[2 * jj]) | (bf16rne(o[2 * jj + 1]) << 16);
        }
        __syncthreads();

        int total = nvalid * 16;
        size_t gbase = (size_t)nbase * 16;
        for (int L = threadIdx.x; L < total; L += 256)
            hb[gbase + L] = sp[(L >> 4) * 17 + (L & 15)];
    } else {
        __shared__ int hloc[NB];
        for (int t = threadIdx.x; t < NB; t += 256) hloc[t] = 0;
        __syncthreads();
        int base = (blockIdx.x - NBLK_EMB) * CHUNK_H;
        int end = base + CHUNK_H; if (end > N_EDGES) end = N_EDGES;
        for (int i = base + threadIdx.x; i < end; i += 256)
            atomicAdd(&hloc[dst[i] >> BSHIFT], 1);
        __syncthreads();
        for (int t = threadIdx.x; t < NB; t += 256)
            if (hloc[t]) atomicAdd(&bcnt[t], hloc[t]);
    }
}

// ---------------------------------------------------------------------------
// K1: single-block exclusive scan of NB bucket counts -> boff, bcur;
//     also zeros the stats replicas
// ---------------------------------------------------------------------------
__global__ void bucket_scan_kernel(const int* __restrict__ bcnt,
                                   int* __restrict__ boff,
                                   int* __restrict__ bcur,
                                   float* __restrict__ stats) {
    int t = threadIdx.x;
    if (t < 64 * NREP) stats[t] = 0.0f;
    __shared__ int s[1024];
    int v0 = (t < NB) ? bcnt[t] : 0;
    s[t] = v0;
    __syncthreads();
#pragma unroll
    for (int o = 1; o < 1024; o <<= 1) {
        int v = (t >= o) ? s[t - o] : 0;
        __syncthreads();
        s[t] += v;
        __syncthreads();
    }
    if (t < NB) {
        int e = s[t] - v0;
        boff[t] = e;
        bcur[t] = e;
    }
    if (t == NB - 1) boff[NB] = s[t];
}

// ---------------------------------------------------------------------------
// K2: binned append, runs ALONE (write-combining needs L2 to itself).
//     packed = (dst & 255) << 24 | src
// ---------------------------------------------------------------------------
__global__ void bin_edges_kernel(const int* __restrict__ src,
                                 const int* __restrict__ dst,
                                 int* __restrict__ bcur,
                                 unsigned int* __restrict__ binned) {
    __shared__ int hloc[NB];
    __shared__ int base[NB];
    __shared__ int lcur[NB];
    for (int t = threadIdx.x; t < NB; t += 512) hloc[t] = 0;
    __syncthreads();

    int cbase = blockIdx.x * CHUNK;
    int cend = cbase + CHUNK; if (cend > N_EDGES) cend = N_EDGES;
    for (int i = cbase + threadIdx.x; i < cend; i += 512)
        atomicAdd(&hloc[dst[i] >> BSHIFT], 1);
    __syncthreads();
    for (int t = threadIdx.x; t < NB; t += 512) {
        int c = hloc[t];
        base[t] = c ? atomicAdd(&bcur[t], c) : 0;
        lcur[t] = 0;
    }
    __syncthreads();
    for (int i = cbase + threadIdx.x; i < cend; i += 512) {
        int d = dst[i];
        int b = d >> BSHIFT;
        int r = atomicAdd(&lcur[b], 1);
        binned[base[b] + r] = ((unsigned)(d & BMASK) << 24) | (unsigned)src[i];
    }
}

// ---------------------------------------------------------------------------
// K3: per-bucket counting sort -> dst-sorted sorted_src + off[] + dis, AND
//     in-place bf16 pre-scale of the bucket's hb rows: hs = h * dis
//     (deletes aggregate's per-edge dis gather; contiguous 16 KB RW).
// ---------------------------------------------------------------------------
__global__ void bucket_csr_kernel(const int* __restrict__ boff,
                                  const unsigned int* __restrict__ binned,
                                  int* __restrict__ sorted_src,
                                  int* __restrict__ off,
                                  float* __restrict__ dis,
                                  unsigned* __restrict__ hb) {
    __shared__ int s_cnt[256];
    __shared__ int s_scan[256];
    __shared__ int s_cur[256];
    __shared__ float dl[256];
    int b = blockIdx.x;
    int t = threadIdx.x;
    int s0 = boff[b], s1 = boff[b + 1];
    int nbase = b << BSHIFT;
    int nnode = N_NODES - nbase; if (nnode > 256) nnode = 256;

    s_cnt[t] = 0;
    __syncthreads();
    for (int k = s0 + t; k < s1; k += 256)
        atomicAdd(&s_cnt[binned[k] >> 24], 1);
    __syncthreads();

    int v = s_cnt[t];
    s_scan[t] = v;
    __syncthreads();
#pragma unroll
    for (int o = 1; o < 256; o <<= 1) {
        int u = (t >= o) ? s_scan[t - o] : 0;
        __syncthreads();
        s_scan[t] += u;
        __syncthreads();
    }
    int excl = s_scan[t] - v;
    s_cur[t] = excl;
    float d = rsqrtf(1.0f + (float)v);
    dl[t] = d;
    if (t < nnode) {
        off[nbase + t] = s0 + excl;
        dis[nbase + t] = d;
    }
    if (b == NB - 1 && t == 0) off[N_NODES] = N_EDGES;
    __syncthreads();

    // scatter to node-sorted order (writes stay inside 16 KB window)
    for (int k = s0 + t; k < s1; k += 256) {
        unsigned p = binned[k];
        int n = (int)(p >> 24);
        int r = atomicAdd(&s_cur[n], 1);
        sorted_src[s0 + r] = (int)(p & 0xFFFFFFu);
    }

    // in-place bf16 pre-scale of this bucket's hb rows (coalesced 16 KB)
    uint2* hv = reinterpret_cast<uint2*>(hb) + (size_t)nbase * 8;
    for (int tt = t; tt < nnode * 8; tt += 256) {
        uint2 w = hv[tt];
        float dd = dl[tt >> 3];
        w.x = bf16rne(bflo(w.x) * dd) | (bf16rne(bfhi(w.x) * dd) << 16);
        w.y = bf16rne(bflo(w.y) * dd) | (bf16rne(bfhi(w.y) * dd) << 16);
        hv[tt] = w;
    }
}

// ---------------------------------------------------------------------------
// K4: per-node aggregation + fused BN-stats.  8 threads/node, pre-scaled bf16
//     rows (no per-edge dis gather), 8-wide ILP with idx double-buffer:
//     next chunk's indices load while current chunk's rows are gathered.
//     agg[n] = (hs[n] + sum_{in(n)} hs[s]) * dis[n]
// ---------------------------------------------------------------------------
__global__ void aggregate_kernel(const int* __restrict__ off,
                                 const int* __restrict__ sorted_src,
                                 const unsigned* __restrict__ hb,
                                 const float* __restrict__ dis,
                                 float* __restrict__ agg,
                                 float* __restrict__ stats) {
    int t = blockIdx.x * blockDim.x + threadIdx.x;
    int node = t >> 3;
    int c = t & 7;
    bool active = node < N_NODES;

    float4 ps = {0.f, 0.f, 0.f, 0.f};
    float4 pq = {0.f, 0.f, 0.f, 0.f};

    if (active) {
        const uint2* hrow = reinterpret_cast<const uint2*>(hb);
        float dn = dis[node];
        uint2 hp = hrow[(size_t)node * 8 + c];
        float4 a0, a1, a2, a3;
        a0.x = bflo(hp.x); a0.y = bfhi(hp.x);      // self term (pre-scaled)
        a0.z = bflo(hp.y); a0.w = bfhi(hp.y);
        a1 = a2 = a3 = make_float4(0.f, 0.f, 0.f, 0.f);

        int b0 = off[node], e0 = off[node + 1];
        int cnt8 = (e0 - b0) >> 3;
        int k = b0;
        int p0 = 0, p1 = 0, p2 = 0, p3 = 0, p4 = 0, p5 = 0, p6 = 0, p7 = 0;
        if (cnt8 > 0) {
            p0 = sorted_src[k];     p1 = sorted_src[k + 1];
            p2 = sorted_src[k + 2]; p3 = sorted_src[k + 3];
            p4 = sorted_src[k + 4]; p5 = sorted_src[k + 5];
            p6 = sorted_src[k + 6]; p7 = sorted_src[k + 7];
        }
        for (int it = 0; it < cnt8; ++it) {
            int kn = k + 8;
            int n0 = p0, n1 = p1, n2 = p2, n3 = p3;
            int n4 = p4, n5 = p5, n6 = p6, n7 = p7;
            if (it + 1 < cnt8) {                    // prefetch next chunk idx
                n0 = sorted_src[kn];     n1 = sorted_src[kn + 1];
                n2 = sorted_src[kn + 2]; n3 = sorted_src[kn + 3];
                n4 = sorted_src[kn + 4]; n5 = sorted_src[kn + 5];
                n6 = sorted_src[kn + 6]; n7 = sorted_src[kn + 7];
            }
            uint2 v0 = hrow[(size_t)p0 * 8 + c];
            uint2 v1 = hrow[(size_t)p1 * 8 + c];
            uint2 v2 = hrow[(size_t)p2 * 8 + c];
            uint2 v3 = hrow[(size_t)p3 * 8 + c];
            uint2 v4 = hrow[(size_t)p4 * 8 + c];
            uint2 v5 = hrow[(size_t)p5 * 8 + c];
            uint2 v6 = hrow[(size_t)p6 * 8 + c];
            uint2 v7 = hrow[(size_t)p7 * 8 + c];
            a0.x += bflo(v0.x); a0.y += bfhi(v0.x); a0.z += bflo(v0.y); a0.w += bfhi(v0.y);
            a1.x += bflo(v1.x); a1.y += bfhi(v1.x); a1.z += bflo(v1.y); a1.w += bfhi(v1.y);
            a2.x += bflo(v2.x); a2.y += bfhi(v2.x); a2.z += bflo(v2.y); a2.w += bfhi(v2.y);
            a3.x += bflo(v3.x); a3.y += bfhi(v3.x); a3.z += bflo(v3.y); a3.w += bfhi(v3.y);
            a0.x += bflo(v4.x); a0.y += bfhi(v4.x); a0.z += bflo(v4.y); a0.w += bfhi(v4.y);
            a1.x += bflo(v5.x); a1.y += bfhi(v5.x); a1.z += bflo(v5.y); a1.w += bfhi(v5.y);
            a2.x += bflo(v6.x); a2.y += bfhi(v6.x); a2.z += bflo(v6.y); a2.w += bfhi(v6.y);
            a3.x += bflo(v7.x); a3.y += bfhi(v7.x); a3.z += bflo(v7.y); a3.w += bfhi(v7.y);
            p0 = n0; p1 = n1; p2 = n2; p3 = n3;
            p4 = n4; p5 = n5; p6 = n6; p7 = n7;
            k = kn;
        }
        for (; k < e0; ++k) {
            int s = sorted_src[k];
            uint2 v = hrow[(size_t)s * 8 + c];
            a0.x += bflo(v.x); a0.y += bfhi(v.x);
            a0.z += bflo(v.y); a0.w += bfhi(v.y);
        }
        float4 o;
        o.x = (a0.x + a1.x + a2.x + a3.x) * dn;
        o.y = (a0.y + a1.y + a2.y + a3.y) * dn;
        o.z = (a0.z + a1.z + a2.z + a3.z) * dn;
        o.w = (a0.w + a1.w + a2.w + a3.w) * dn;
        reinterpret_cast<float4*>(agg)[(size_t)node * 8 + c] = o;
        ps = o;
        pq.x = o.x * o.x; pq.y = o.y * o.y; pq.z = o.z * o.z; pq.w = o.w * o.w;
    }

    // block-level stats reduce (all 256 threads reach barriers)
    __shared__ float S[256 * 4];
    __shared__ float Q[256 * 4];
    S[threadIdx.x * 4 + 0] = ps.x; S[threadIdx.x * 4 + 1] = ps.y;
    S[threadIdx.x * 4 + 2] = ps.z; S[threadIdx.x * 4 + 3] = ps.w;
    Q[threadIdx.x * 4 + 0] = pq.x; Q[threadIdx.x * 4 + 1] = pq.y;
    Q[threadIdx.x * 4 + 2] = pq.z; Q[threadIdx.x * 4 + 3] = pq.w;
    __syncthreads();
    if (threadIdx.x < 32) {
        int cc = threadIdx.x >> 2, j = threadIdx.x & 3;
        float s = 0.0f, q = 0.0f;
#pragma unroll
        for (int w = 0; w < 32; ++w) {
            int tid = (w << 3) | cc;
            s += S[tid * 4 + j];
            q += Q[tid * 4 + j];
        }
        float* rep = stats + 64 * (blockIdx.x & (NREP - 1));
        atomicAdd(&rep[threadIdx.x], s);
        atomicAdd(&rep[32 + threadIdx.x], q);
    }
}

// ---------------------------------------------------------------------------
// K5: out = relu(agg*A + B) @ W_cls + b_cls   (BN fold from NREP stat replicas)
// ---------------------------------------------------------------------------
__global__ void cls_kernel(const float* __restrict__ agg,
                           const float* __restrict__ stats,
                           const float* __restrict__ gamma,
                           const float* __restrict__ beta,
                           const float* __restrict__ W_cls,
                           const float* __restrict__ b_cls,
                           float* __restrict__ out) {
    __shared__ float sA[HID];
    __shared__ float sB[HID];
    __shared__ float sW[HID * N_CLS];
    __shared__ float sb[N_CLS];
    if (threadIdx.x < HID) {
        float sum = 0.0f, sq = 0.0f;
#pragma unroll
        for (int r = 0; r < NREP; ++r) {
            sum += stats[r * 64 + threadIdx.x];
            sq  += stats[r * 64 + 32 + threadIdx.x];
        }
        const float invN = 1.0f / (float)N_NODES;
        float mean = sum * invN;
        float var = sq * invN - mean * mean;
        float inv = rsqrtf(var + BN_EPS);
        float A = gamma[threadIdx.x] * inv;
        sA[threadIdx.x] = A;
        sB[threadIdx.x] = beta[threadIdx.x] - mean * A;
    }
    for (int t = threadIdx.x; t < HID * N_CLS; t += blockDim.x) sW[t] = W_cls[t];
    if (threadIdx.x < N_CLS) sb[threadIdx.x] = b_cls[threadIdx.x];
    __syncthreads();

    int i = blockIdx.x * blockDim.x + threadIdx.x;
    if (i >= N_NODES) return;

    float acc[N_CLS];
#pragma unroll
    for (int c = 0; c < N_CLS; ++c) acc[c] = sb[c];
#pragma unroll
    for (int f = 0; f < HID; ++f) {
        float t = fmaxf(fmaf(agg[(size_t)i * HID + f], sA[f], sB[f]), 0.0f);
#pragma unroll
        for (int c = 0; c < N_CLS; ++c) acc[c] = fmaf(t, sW[f * N_CLS + c], acc[c]);
    }
#pragma unroll
    for (int c = 0; c < N_CLS; ++c) out[(size_t)i * N_CLS + c] = acc[c];
}

// ---------------------------------------------------------------------------
extern "C" void kernel_launch(void* const* d_in, const int* in_sizes, int n_in,
                              void* d_out, int out_size, void* d_ws, size_t ws_size,
                              hipStream_t stream) {
    const float* x     = (const float*)d_in[0];
    const int*   edge  = (const int*)d_in[1];   // [2, E] int32
    const float* W_emb = (const float*)d_in[2];
    const float* b_emb = (const float*)d_in[3];
    const float* W_gcn = (const float*)d_in[4];
    // d_in[5] = b_gcn: cancels exactly in BatchNorm -> skip
    const float* gamma = (const float*)d_in[6];
    const float* beta  = (const float*)d_in[7];
    const float* W_cls = (const float*)d_in[8];
    const float* b_cls = (const float*)d_in[9];
    float* out = (float*)d_out;

    // workspace layout (~49 MB)
    unsigned*     hb         = (unsigned*)d_ws;                 // N*HID/2 uints (bf16 x2)
    float*        agg        = (float*)(hb + (size_t)N_NODES * HID / 2);  // N*HID
    float*        dis        = agg + (size_t)N_NODES * HID;     // N
    int*          off        = (int*)(dis + N_NODES);           // N+1
    int*          bcnt       = off + N_NODES + 1;               // NB
    int*          boff       = bcnt + NB;                       // NB+1
    int*          bcur       = boff + NB + 1;                   // NB
    unsigned int* binned     = (unsigned int*)(bcur + NB);      // E
    int*          sorted_src = (int*)(binned + N_EDGES);        // E
    float*        stats      = (float*)(sorted_src + N_EDGES);  // 64*NREP

    hipMemsetAsync(bcnt, 0, NB * sizeof(int), stream);

    const int* src = edge;
    const int* dst = edge + N_EDGES;

    embed_hist_kernel<<<NBLK_EMB + NBLK_H, 256, 0, stream>>>(x, W_emb, b_emb, W_gcn,
                                                             hb, dst, bcnt);
    bucket_scan_kernel<<<1, 1024, 0, stream>>>(bcnt, boff, bcur, stats);
    bin_edges_kernel<<<NBLK_BIN, 512, 0, stream>>>(src, dst, bcur, binned);
    bucket_csr_kernel<<<NB, 256, 0, stream>>>(boff, binned, sorted_src, off, dis, hb);
    aggregate_kernel<<<(N_NODES * 8 + 255) / 256, 256, 0, stream>>>(off, sorted_src,
                                                                    hb, dis, agg, stats);
    cls_kernel<<<(N_NODES + 255) / 256, 256, 0, stream>>>(agg, stats, gamma, beta,
                                                          W_cls, b_cls, out);
}